// Round 6
// baseline (126.597 us; speedup 1.0000x reference)
//
#include <hip/hip_runtime.h>
#include <hip/hip_bf16.h>

#define MDIM 8192
#define KDIM 512
#define BM 128
#define BN 128
#define BK 64
#define NKT 8   // K-tiles of 64

typedef __attribute__((ext_vector_type(8))) short short8;
typedef __attribute__((ext_vector_type(4))) float f32x4;
typedef __attribute__((ext_vector_type(8))) unsigned short ushort8;

__device__ __forceinline__ unsigned short f32_to_bf16_rne(float f) {
    unsigned int u = __float_as_uint(f);
    u += 0x7FFFu + ((u >> 16) & 1u);
    return (unsigned short)(u >> 16);
}
__device__ __forceinline__ float bf16_to_f32(unsigned short s) {
    return __uint_as_float(((unsigned int)s) << 16);
}

__device__ __forceinline__ void gload16(const void* g, void* l) {
    __builtin_amdgcn_global_load_lds(
        (const __attribute__((address_space(1))) void*)g,
        (__attribute__((address_space(3))) void*)l,
        16, 0, 0);
}

// Kernel 1: fp32 -> bf16 into ws + sq[row] = sum(bf16(x)^2) (fp32).
__global__ __launch_bounds__(256) void rbf_convert(const float* __restrict__ x,
                                                   unsigned short* __restrict__ xb,
                                                   float* __restrict__ sq) {
    const int lane = threadIdx.x & 63;
    const int wave = threadIdx.x >> 6;
    const int row  = blockIdx.x * 4 + wave;

    const float* xr = x + (size_t)row * KDIM + lane * 8;
    float4 v0 = *(const float4*)(xr);
    float4 v1 = *(const float4*)(xr + 4);
    float vals[8] = {v0.x, v0.y, v0.z, v0.w, v1.x, v1.y, v1.z, v1.w};

    ushort8 packed;
    float s = 0.f;
#pragma unroll
    for (int j = 0; j < 8; ++j) {
        unsigned short b = f32_to_bf16_rne(vals[j]);
        packed[j] = b;
        float f = bf16_to_f32(b);
        s += f * f;
    }
    *(ushort8*)(xb + (size_t)row * KDIM + lane * 8) = packed;

#pragma unroll
    for (int off = 32; off > 0; off >>= 1) s += __shfl_xor(s, off, 64);
    if (lane == 0) sq[row] = s;
}

// triangular XCD-affine enumeration (verified R5): XCD x owns tile-rows
// {4x..4x+3, 60-4x..63-4x} (260 tiles each); band-major sweep.
__device__ __forceinline__ void tile_of(int xcd, int kk, int& tr, int& tc) {
    tr = 0; tc = 0;
    bool found = false;
#pragma unroll 1
    for (int b = 0; b < 8 && !found; ++b) {
#pragma unroll 1
        for (int i = 0; i < 8; ++i) {
            const int rr = (i < 4) ? (4 * xcd + i) : (60 - 4 * xcd + (i - 4));
            int n = rr - 8 * b + 1;
            n = n < 0 ? 0 : (n > 8 ? 8 : n);
            if (kk < n) { tr = rr; tc = 8 * b + kk; found = true; break; }
            kk -= n;
        }
    }
}

// Kernel 2: symmetric RBF, persistent 4-tile blocks (520 blocks, 2/CU).
// Per tile: dbuf K-loop -> exp -> LDS transpose -> dual 256B-coalesced
// regular stores; tile t's write-back drains under tile t+1's K-loop.
__global__ __launch_bounds__(256, 2) void rbf_gemm(const unsigned short* __restrict__ xb,
                                                   const float* __restrict__ sq,
                                                   float* __restrict__ out) {
    __shared__ char lds[65536];   // dbuf: [buf][A 16K | B 16K]; reused by epilogue

    const int t    = threadIdx.x;
    const int lane = t & 63;
    const int wave = t >> 6;
    const int wr   = wave >> 1;   // 0..1
    const int wc   = wave & 1;    // 0..1

    const int xcd = blockIdx.x & 7;
    const int grp = blockIdx.x >> 3;   // 0..64, 4 tiles each

    // staging: thread t -> LDS row t>>3, slot t&7 linear dest,
    // global source slot XOR-swizzled (T2 both-sides involution, verified).
    const int trow = t >> 3;
    const int sx   = ((t & 7) ^ (trow & 7)) * 16;

    // fragment coords
    const int fr = lane & 15;
    const int fo = lane >> 4;
    const int k7 = fr & 7;
    const int cg = lane >> 4;
    const int cl = lane & 15;

    char* ldsw = lds + wave * 1024;
    float* ldsf = (float*)lds + wave * 4096;   // per-wave 16 KB epilogue region

#pragma unroll 1
    for (int tt = 0; tt < 4; ++tt) {
        int tr, tc;
        tile_of(xcd, grp * 4 + tt, tr, tc);
        const int brow = tr * 128;
        const int bcol = tc * 128;

        const char* gA = (const char*)xb + (size_t)(brow + trow) * 1024 + sx;
        const char* gB = (const char*)xb + (size_t)(bcol + trow) * 1024 + sx;

        f32x4 acc[4][4] = {};

        __syncthreads();   // prior tile's epilogue LDS reads done (all waves)

        // prologue: stage K-tile 0 into buf 0
#pragma unroll
        for (int u = 0; u < 4; ++u) {
            gload16(gA + (size_t)u * 32768, ldsw + u * 4096);
            gload16(gB + (size_t)u * 32768, ldsw + 16384 + u * 4096);
        }
        __syncthreads();

#pragma unroll
        for (int i = 0; i < NKT; ++i) {
            const int cb = i & 1;
            if (i < NKT - 1) {
                const size_t koff = (size_t)(i + 1) * 128;
                char* dst = ldsw + (cb ^ 1) * 32768;
#pragma unroll
                for (int u = 0; u < 4; ++u) {
                    gload16(gA + (size_t)u * 32768 + koff, dst + u * 4096);
                    gload16(gB + (size_t)u * 32768 + koff, dst + 16384 + u * 4096);
                }
            }
            const char* Ab = lds + cb * 32768;
            const char* Bb = lds + cb * 32768 + 16384;
#pragma unroll
            for (int ks = 0; ks < 2; ++ks) {
                const int cxa = ((ks * 4 + fo) ^ k7) * 16;
                short8 a[4];
#pragma unroll
                for (int m = 0; m < 4; ++m)
                    a[m] = *(const short8*)(Ab + (wr * 64 + m * 16 + fr) * 128 + cxa);
#pragma unroll
                for (int n = 0; n < 4; ++n) {
                    short8 b = *(const short8*)(Bb + (wc * 64 + n * 16 + fr) * 128 + cxa);
#pragma unroll
                    for (int m = 0; m < 4; ++m)
                        acc[m][n] = __builtin_amdgcn_mfma_f32_16x16x32_bf16(a[m], b, acc[m][n], 0, 0, 0);
                }
            }
            __syncthreads();
        }

        // ---- epilogue ----
        float sqr[16], sqc[4];
#pragma unroll
        for (int m = 0; m < 4; ++m)
#pragma unroll
            for (int j = 0; j < 4; ++j)
                sqr[m * 4 + j] = sq[brow + wr * 64 + m * 16 + cg * 4 + j];
#pragma unroll
        for (int n = 0; n < 4; ++n)
            sqc[n] = sq[bcol + wc * 64 + n * 16 + cl];

        // exp once, in MFMA C-layout
#pragma unroll
        for (int m = 0; m < 4; ++m)
#pragma unroll
            for (int n = 0; n < 4; ++n)
#pragma unroll
                for (int j = 0; j < 4; ++j) {
                    const float v = fmaf(acc[m][n][j], 1.44269504f,
                                         -0.72134752f * (sqr[m * 4 + j] + sqc[n]));
                    acc[m][n][j] = __builtin_exp2f(fminf(v, 0.f));
                }

        // LDS transpose (16B-group XOR swizzle, verified)
        asm volatile("" ::: "memory");
#pragma unroll
        for (int m = 0; m < 4; ++m) {
#pragma unroll
            for (int j = 0; j < 4; ++j) {
                const int r = m * 16 + cg * 4 + j;
                const int sxr = r & 7;
#pragma unroll
                for (int n = 0; n < 4; ++n) {
                    const int c = n * 16 + cl;
                    ldsf[r * 64 + ((((c >> 2) ^ sxr) << 2) | (c & 3))] = acc[m][n][j];
                }
            }
        }
        asm volatile("" ::: "memory");   // per-wave region; pin program order

        // normal tile: 16 lanes x 16B along c -> 4 x 256B segments / instr
        {
            const int col0 = bcol + wc * 64 + cl * 4;
#pragma unroll
            for (int k = 0; k < 16; ++k) {
                const int r = k * 4 + cg;
                f32x4 v = *(const f32x4*)&ldsf[r * 64 + ((cl ^ (r & 7)) << 2)];
                const int row = brow + wr * 64 + r;
                *(f32x4*)(out + (size_t)row * MDIM + col0) = v;
            }
        }

        // transposed tile (tr!=tc): column-wise ldsf reads -> same 256B pattern
        if (tr != tc) {
            const int r0 = cl * 4;
            float* obase = out + (size_t)(bcol + wc * 64) * MDIM + brow + wr * 64 + r0;
#pragma unroll
            for (int k = 0; k < 16; ++k) {
                f32x4 v;
#pragma unroll
                for (int j = 0; j < 4; ++j) {
                    const int r = r0 + j;
                    v[j] = ldsf[r * 64 + (((k ^ (r & 7)) << 2) | cg)];
                }
                const int c = k * 4 + cg;
                *(f32x4*)(obase + (size_t)c * MDIM) = v;
            }
        }
    }
}

extern "C" void kernel_launch(void* const* d_in, const int* in_sizes, int n_in,
                              void* d_out, int out_size, void* d_ws, size_t ws_size,
                              hipStream_t stream) {
    const float* x = (const float*)d_in[0];
    float* out = (float*)d_out;

    float* sq = (float*)d_ws;
    unsigned short* xb = (unsigned short*)((char*)d_ws + MDIM * sizeof(float));

    rbf_convert<<<MDIM / 4, 256, 0, stream>>>(x, xb, sq);
    rbf_gemm<<<dim3(520), 256, 0, stream>>>(xb, sq, out);
}

// Round 7
// 86.578 us; speedup vs baseline: 1.4622x; 1.4622x over previous
//
#include <hip/hip_runtime.h>
#include <hip/hip_bf16.h>

#define MDIM 8192
#define KDIM 512
#define BM 128
#define BN 128
#define BK 64
#define NKT 8   // K-tiles of 64

typedef __attribute__((ext_vector_type(8))) short short8;
typedef __attribute__((ext_vector_type(4))) float f32x4;
typedef __attribute__((ext_vector_type(8))) unsigned short ushort8;

__device__ __forceinline__ unsigned short f32_to_bf16_rne(float f) {
    unsigned int u = __float_as_uint(f);
    u += 0x7FFFu + ((u >> 16) & 1u);
    return (unsigned short)(u >> 16);
}
__device__ __forceinline__ float bf16_to_f32(unsigned short s) {
    return __uint_as_float(((unsigned int)s) << 16);
}

__device__ __forceinline__ void gload16(const void* g, void* l) {
    __builtin_amdgcn_global_load_lds(
        (const __attribute__((address_space(1))) void*)g,
        (__attribute__((address_space(3))) void*)l,
        16, 0, 0);
}

// Kernel 1: fp32 -> bf16 into ws + sq[row] = sum(bf16(x)^2) (fp32).
__global__ __launch_bounds__(256) void rbf_convert(const float* __restrict__ x,
                                                   unsigned short* __restrict__ xb,
                                                   float* __restrict__ sq) {
    const int lane = threadIdx.x & 63;
    const int wave = threadIdx.x >> 6;
    const int row  = blockIdx.x * 4 + wave;

    const float* xr = x + (size_t)row * KDIM + lane * 8;
    float4 v0 = *(const float4*)(xr);
    float4 v1 = *(const float4*)(xr + 4);
    float vals[8] = {v0.x, v0.y, v0.z, v0.w, v1.x, v1.y, v1.z, v1.w};

    ushort8 packed;
    float s = 0.f;
#pragma unroll
    for (int j = 0; j < 8; ++j) {
        unsigned short b = f32_to_bf16_rne(vals[j]);
        packed[j] = b;
        float f = bf16_to_f32(b);
        s += f * f;
    }
    *(ushort8*)(xb + (size_t)row * KDIM + lane * 8) = packed;

#pragma unroll
    for (int off = 32; off > 0; off >>= 1) s += __shfl_xor(s, off, 64);
    if (lane == 0) sq[row] = s;
}

// triangular XCD-affine enumeration (verified R5): XCD x owns tile-rows
// {4x..4x+3, 60-4x..63-4x} (260 tiles each); band-major sweep.
__device__ __forceinline__ void tile_of(int xcd, int kk, int& tr, int& tc) {
    tr = 0; tc = 0;
    bool found = false;
#pragma unroll 1
    for (int b = 0; b < 8 && !found; ++b) {
#pragma unroll 1
        for (int i = 0; i < 8; ++i) {
            const int rr = (i < 4) ? (4 * xcd + i) : (60 - 4 * xcd + (i - 4));
            int n = rr - 8 * b + 1;
            n = n < 0 ? 0 : (n > 8 ? 8 : n);
            if (kk < n) { tr = rr; tc = 8 * b + kk; found = true; break; }
            kk -= n;
        }
    }
}

// Kernel 2: symmetric RBF, lower-triangle tiles (2080 blocks), 32 KiB LDS
// single-buffered K-loop -> 4 blocks/CU so store drains overlap other
// blocks' K-loops. nt stores (load-bearing: R4 gain, R6 regression).
__global__ __launch_bounds__(256, 4) void rbf_gemm(const unsigned short* __restrict__ xb,
                                                   const float* __restrict__ sq,
                                                   float* __restrict__ out) {
    __shared__ char lds[32768];   // K-loop: A 16K | B 16K; epilogue: 4 waves x 8K

    const int t    = threadIdx.x;
    const int lane = t & 63;
    const int wave = t >> 6;
    const int wr   = wave >> 1;   // 0..1
    const int wc   = wave & 1;    // 0..1

    int tr, tc;
    tile_of(blockIdx.x & 7, blockIdx.x >> 3, tr, tc);
    const int brow = tr * 128;
    const int bcol = tc * 128;

    // staging: thread t -> LDS row t>>3 (+32/issue), slot t&7 linear dest,
    // global source slot XOR-swizzled (T2 both-sides involution, verified).
    const int trow = t >> 3;
    const int sx   = ((t & 7) ^ (trow & 7)) * 16;

    // fragment coords
    const int fr = lane & 15;
    const int fo = lane >> 4;
    const int k7 = fr & 7;
    const int cg = lane >> 4;
    const int cl = lane & 15;

    f32x4 acc[4][4] = {};

    const char* gA = (const char*)xb + (size_t)(brow + trow) * 1024 + sx;
    const char* gB = (const char*)xb + (size_t)(bcol + trow) * 1024 + sx;
    char* ldsw = lds + wave * 1024;

#pragma unroll 1
    for (int i = 0; i < NKT; ++i) {
        if (i) __syncthreads();           // tile i-1 reads complete
        const size_t koff = (size_t)i * 128;
#pragma unroll
        for (int u = 0; u < 4; ++u) {
            gload16(gA + (size_t)u * 32768 + koff, ldsw + u * 4096);
            gload16(gB + (size_t)u * 32768 + koff, ldsw + 16384 + u * 4096);
        }
        __syncthreads();                  // vmcnt(0)+barrier: tile i visible
#pragma unroll
        for (int ks = 0; ks < 2; ++ks) {
            const int cxa = ((ks * 4 + fo) ^ k7) * 16;
            short8 a[4];
#pragma unroll
            for (int m = 0; m < 4; ++m)
                a[m] = *(const short8*)(lds + (wr * 64 + m * 16 + fr) * 128 + cxa);
#pragma unroll
            for (int n = 0; n < 4; ++n) {
                short8 b = *(const short8*)(lds + 16384 + (wc * 64 + n * 16 + fr) * 128 + cxa);
#pragma unroll
                for (int m = 0; m < 4; ++m)
                    acc[m][n] = __builtin_amdgcn_mfma_f32_16x16x32_bf16(a[m], b, acc[m][n], 0, 0, 0);
            }
        }
    }
    __syncthreads();   // all K-loop LDS reads done before epilogue reuse

    // ---- epilogue ----
    float sqr[16], sqc[4];
#pragma unroll
    for (int m = 0; m < 4; ++m)
#pragma unroll
        for (int j = 0; j < 4; ++j)
            sqr[m * 4 + j] = sq[brow + wr * 64 + m * 16 + cg * 4 + j];
#pragma unroll
    for (int n = 0; n < 4; ++n)
        sqc[n] = sq[bcol + wc * 64 + n * 16 + cl];

    // exp once, in MFMA C-layout
#pragma unroll
    for (int m = 0; m < 4; ++m)
#pragma unroll
        for (int n = 0; n < 4; ++n)
#pragma unroll
            for (int j = 0; j < 4; ++j) {
                const float v = fmaf(acc[m][n][j], 1.44269504f,
                                     -0.72134752f * (sqr[m * 4 + j] + sqc[n]));
                acc[m][n][j] = __builtin_exp2f(fminf(v, 0.f));
            }

    // transposed tile (tr!=tc): direct from registers — lane's j-axis is
    // row-contiguous => f32x4 nt stores (verified R5 path).
    if (tr != tc) {
#pragma unroll
        for (int n = 0; n < 4; ++n) {
            float* orow = out + (size_t)(bcol + wc * 64 + n * 16 + cl) * MDIM
                              + brow + wr * 64 + cg * 4;
#pragma unroll
            for (int m = 0; m < 4; ++m)
                __builtin_nontemporal_store(acc[m][n], (f32x4*)(orow + m * 16));
        }
    }

    // normal tile: per-wave 8 KiB LDS transpose in two 32-row halves
    // (same 16B-group XOR swizzle; 32 ≡ 0 mod 8 so r&7 terms unchanged).
    float* ldsf = (float*)lds + wave * 2048;
    const int col0 = bcol + wc * 64 + cl * 4;
#pragma unroll
    for (int h = 0; h < 2; ++h) {
        asm volatile("" ::: "memory");
#pragma unroll
        for (int mh = 0; mh < 2; ++mh) {
            const int m = h * 2 + mh;
#pragma unroll
            for (int j = 0; j < 4; ++j) {
                const int rl = mh * 16 + cg * 4 + j;
                const int sxr = rl & 7;
#pragma unroll
                for (int n = 0; n < 4; ++n) {
                    const int c = n * 16 + cl;
                    ldsf[rl * 64 + ((((c >> 2) ^ sxr) << 2) | (c & 3))] = acc[m][n][j];
                }
            }
        }
        asm volatile("" ::: "memory");   // per-wave region, in-order DS pipe
#pragma unroll
        for (int k = 0; k < 8; ++k) {
            const int rl = k * 4 + cg;
            f32x4 v = *(const f32x4*)&ldsf[rl * 64 + ((cl ^ (rl & 7)) << 2)];
            const int row = brow + wr * 64 + h * 32 + rl;
            __builtin_nontemporal_store(v, (f32x4*)(out + (size_t)row * MDIM + col0));
        }
        asm volatile("" ::: "memory");   // reads precede next half's overwrites
    }
}

extern "C" void kernel_launch(void* const* d_in, const int* in_sizes, int n_in,
                              void* d_out, int out_size, void* d_ws, size_t ws_size,
                              hipStream_t stream) {
    const float* x = (const float*)d_in[0];
    float* out = (float*)d_out;

    float* sq = (float*)d_ws;
    unsigned short* xb = (unsigned short*)((char*)d_ws + MDIM * sizeof(float));

    rbf_convert<<<MDIM / 4, 256, 0, stream>>>(x, xb, sq);
    rbf_gemm<<<dim3(2080), 256, 0, stream>>>(xb, sq, out);
}